// Round 1
// baseline (48996.536 us; speedup 1.0000x reference)
//
#include <hip/hip_runtime.h>

// Output layout (flat f32, reference return order):
//   xhat  : B*L*N   = 13,107,200  @ 0
//   mu    : B*D     =      4,096  @ 13,107,200
//   logvar: B*D     =      4,096  @ 13,111,296
//   z_traj: B*L*D   =    819,200  @ 13,115,392
//   zdiff : B*(L-1)*D =  815,104  @ 13,934,592
#define OFF_MU   13107200
#define OFF_LV   13111296
#define OFF_ZT   13115392
#define OFF_ZD   13934592

typedef float v2f __attribute__((ext_vector_type(2)));

__device__ __forceinline__ float silu_f(float x) {
    return x / (1.0f + __expf(-x));
}

__device__ __forceinline__ float readlane_f(float v, int l) {
    return __uint_as_float(__builtin_amdgcn_readlane(__float_as_uint(v), l));
}

__device__ __forceinline__ v2f fma2(v2f a, v2f b, v2f c) {
    return __builtin_elementwise_fma(a, b, c);
}

// sum of x over lanes 0..15 (x must hold the 16 values in lanes 0..15).
// Uses readlane -> SGPR chain: no LDS/bpermute latency, uniform result.
__device__ __forceinline__ float sum16_rl(float x) {
    float a = readlane_f(x, 0);
#pragma unroll
    for (int k = 1; k < 16; ++k) a += readlane_f(x, k);
    return a;
}

// ---------------------------------------------------------------------------
// Encoder: one block per batch row. x0(256) -> 512 -> 256 -> 128 -> mu/lv(16)
// Writes mu, logvar, and z0 into z_traj[:,0,:].  (unchanged — negligible cost)
// ---------------------------------------------------------------------------
__global__ __launch_bounds__(256) void enc_kernel(
    const float* __restrict__ xseq, const float* __restrict__ eps,
    const float* __restrict__ w1, const float* __restrict__ b1,
    const float* __restrict__ w2, const float* __restrict__ b2,
    const float* __restrict__ w3, const float* __restrict__ b3,
    const float* __restrict__ muw, const float* __restrict__ mub,
    const float* __restrict__ lvw, const float* __restrict__ lvb,
    float* __restrict__ out)
{
    __shared__ float xr[256];
    __shared__ float h1[512];
    __shared__ float h2[256];
    __shared__ float h3[128];

    const int t = threadIdx.x;
    const int b = blockIdx.x;

    xr[t] = xseq[b * (200 * 256) + t];   // x_seq[b, 0, :]
    __syncthreads();

    {
        float acc0 = b1[t], acc1 = b1[t + 256];
        for (int i = 0; i < 256; ++i) {
            float xv = xr[i];
            acc0 = fmaf(xv, w1[i * 512 + t],       acc0);
            acc1 = fmaf(xv, w1[i * 512 + t + 256], acc1);
        }
        h1[t]       = fmaxf(acc0, 0.0f);
        h1[t + 256] = fmaxf(acc1, 0.0f);
    }
    __syncthreads();

    {
        float acc = b2[t];
        for (int i = 0; i < 512; ++i) acc = fmaf(h1[i], w2[i * 256 + t], acc);
        h2[t] = fmaxf(acc, 0.0f);
    }
    __syncthreads();

    if (t < 128) {
        float acc = b3[t];
        for (int i = 0; i < 256; ++i) acc = fmaf(h2[i], w3[i * 128 + t], acc);
        h3[t] = fmaxf(acc, 0.0f);
    }
    __syncthreads();

    if (t < 16) {
        float mu = mub[t], lv = lvb[t];
        for (int i = 0; i < 128; ++i) {
            float hv = h3[i];
            mu = fmaf(hv, muw[i * 16 + t], mu);
            lv = fmaf(hv, lvw[i * 16 + t], lv);
        }
        out[OFF_MU + b * 16 + t] = mu;
        out[OFF_LV + b * 16 + t] = lv;
        float z0 = mu + __expf(0.5f * lv) * eps[b * 16 + t];
        out[OFF_ZT + b * 3200 + t] = z0;   // z_traj[b, 0, :]
    }
}

// ---------------------------------------------------------------------------
// ODE integrator v2: ONE WAVE (64 threads) per batch element.
//   - workgroup == wave  =>  __syncthreads() is just s_waitcnt (s_barrier elided)
//   - z, k1..k6 replicated per lane (d = lane&15, 4 identical copies):
//     dopri stage combos are per-lane scalar FMAs, no broadcast needed.
//   - zarg broadcast lanes0..15 -> SGPRs via v_readlane (no LDS round trip).
//   - w1/w2/w3 register-resident; L2/L3 use v_pk_fma_f32 (2 FLOP/instr).
//   - L3: K=128 split over 4 lane-groups (bank-staggered b128 reads), reduced
//     with 2 shfl_xor hops; LN sums via readlane chains (two-pass variance).
// Per-lane hidden cols: j0 = lane, j1 = lane + 64.
// ---------------------------------------------------------------------------
__global__ __launch_bounds__(64, 1) void ode_kernel(
    const float* __restrict__ tvec,
    const float* __restrict__ ow1, const float* __restrict__ ob1,
    const float* __restrict__ ow2, const float* __restrict__ ob2,
    const float* __restrict__ ow3, const float* __restrict__ ob3,
    const float* __restrict__ lng, const float* __restrict__ lnb,
    float* __restrict__ out)
{
    __shared__ __align__(16) float a1s[128];
    __shared__ __align__(16) float a2s[128];

    const int lane = threadIdx.x;
    const int b    = blockIdx.x;
    const int d    = lane & 15;      // owned z-dim (replicated x4)
    const int grp  = lane >> 4;      // L3 K-chunk (32 wide)
    const int j0   = lane;
    const int j1   = lane + 64;

    // ---- register-resident weights -------------------------------------
    float w1r0[16], w1r1[16];
#pragma unroll
    for (int k = 0; k < 16; ++k) {
        w1r0[k] = ow1[k * 128 + j0];
        w1r1[k] = ow1[k * 128 + j1];
    }
    v2f w2v0[64], w2v1[64];          // pairs along K: {w2[2q][j], w2[2q+1][j]}
#pragma unroll
    for (int q = 0; q < 64; ++q) {
        v2f t0 = { ow2[(2 * q) * 128 + j0], ow2[(2 * q + 1) * 128 + j0] };
        v2f t1 = { ow2[(2 * q) * 128 + j1], ow2[(2 * q + 1) * 128 + j1] };
        w2v0[q] = t0;
        w2v1[q] = t1;
    }
    v2f w3v[16];                     // chunk grp, stored in staggered read order
#pragma unroll
    for (int qq = 0; qq < 8; ++qq) {
        int q  = (qq + 2 * grp) & 7;       // bank-stagger: groups hit disjoint banks
        int k0 = 32 * grp + 4 * q;
        v2f t0 = { ow3[(k0 + 0) * 16 + d], ow3[(k0 + 1) * 16 + d] };
        v2f t1 = { ow3[(k0 + 2) * 16 + d], ow3[(k0 + 3) * 16 + d] };
        w3v[2 * qq]     = t0;
        w3v[2 * qq + 1] = t1;
    }
    const float b1j0 = ob1[j0], b1j1 = ob1[j1];
    const float b2j0 = ob2[j0], b2j1 = ob2[j1];
    const float b3d  = ob3[d];
    const float lngd = lng[d], lnbd = lnb[d];

    float* ztraj = out + OFF_ZT + b * 3200;   // [200][16]
    float* zdiff = out + OFF_ZD + b * 3184;   // [199][16]

    float z = ztraj[d];                       // z0 from encoder, replicated x4

    // one evaluation of f(za); za holds zarg[d] per lane (replicated x4).
    auto feval = [&](float za) -> float {
        // L1: broadcast zarg to SGPRs, 2 cols/lane, K=16
        float acc0 = b1j0, acc1 = b1j1;
#pragma unroll
        for (int k = 0; k < 16; ++k) {
            float zk = readlane_f(za, k);      // wave-uniform -> SGPR operand
            acc0 = fmaf(zk, w1r0[k], acc0);
            acc1 = fmaf(zk, w1r1[k], acc1);
        }
        a1s[j0] = silu_f(acc0);
        a1s[j1] = silu_f(acc1);
        __syncthreads();                       // single wave: waitcnt only

        // L2: 2 cols/lane, K=128, packed FMA; a1 via broadcast b128 reads
        v2f p0 = { b2j0, 0.0f };
        v2f p1 = { b2j1, 0.0f };
        const float4* a14 = (const float4*)a1s;
#pragma unroll
        for (int q = 0; q < 32; ++q) {
            float4 av = a14[q];
            v2f lo = { av.x, av.y };
            v2f hi = { av.z, av.w };
            p0 = fma2(lo, w2v0[2 * q],     p0);
            p0 = fma2(hi, w2v0[2 * q + 1], p0);
            p1 = fma2(lo, w2v1[2 * q],     p1);
            p1 = fma2(hi, w2v1[2 * q + 1], p1);
        }
        float a20 = silu_f(p0.x + p0.y);
        float a21 = silu_f(p1.x + p1.y);
        a2s[j0] = a20;
        a2s[j1] = a21;
        __syncthreads();

        // L3: output d, K-chunk grp (32 wide), bank-staggered reads
        v2f pp = { 0.0f, 0.0f };
        const float4* a24 = (const float4*)(a2s + 32 * grp);
#pragma unroll
        for (int qq = 0; qq < 8; ++qq) {
            int q = (qq + 2 * grp) & 7;        // matches w3v load order
            float4 av = a24[q];
            v2f lo = { av.x, av.y };
            v2f hi = { av.z, av.w };
            pp = fma2(lo, w3v[2 * qq],     pp);
            pp = fma2(hi, w3v[2 * qq + 1], pp);
        }
        float pd = pp.x + pp.y;
        pd += __shfl_xor(pd, 16);              // combine chunk pairs
        pd += __shfl_xor(pd, 32);              // full K sum; replicated x4
        float dz = pd + b3d;

        // LayerNorm over d=0..15, two-pass (matches reference variance form)
        float m  = sum16_rl(dz) * 0.0625f;
        float df = dz - m;
        float v  = sum16_rl(df * df) * 0.0625f;
        return df * rsqrtf(v + 1e-5f) * lngd + lnbd;
    };

    for (int l = 0; l < 199; ++l) {
        const float dt = tvec[l + 1] - tvec[l];
        const float h  = dt * 0.125f;          // dt / K, K=8 (exact)
        const float zstart = z;
        for (int s = 0; s < 8; ++s) {
            float k1 = feval(z);
            float k2 = feval(z + h * (k1 * (float)(1.0 / 5.0)));
            float k3 = feval(z + h * ((float)(3.0 / 40.0) * k1 + (float)(9.0 / 40.0) * k2));
            float k4 = feval(z + h * ((float)(44.0 / 45.0) * k1 - (float)(56.0 / 15.0) * k2
                                    + (float)(32.0 / 9.0) * k3));
            float k5 = feval(z + h * ((float)(19372.0 / 6561.0) * k1 - (float)(25360.0 / 2187.0) * k2
                                    + (float)(64448.0 / 6561.0) * k3 - (float)(212.0 / 729.0) * k4));
            float k6 = feval(z + h * ((float)(9017.0 / 3168.0) * k1 - (float)(355.0 / 33.0) * k2
                                    + (float)(46732.0 / 5247.0) * k3 + (float)(49.0 / 176.0) * k4
                                    - (float)(5103.0 / 18656.0) * k5));
            z = z + h * ((float)(35.0 / 384.0) * k1 + (float)(500.0 / 1113.0) * k3
                       + (float)(125.0 / 192.0) * k4 - (float)(2187.0 / 6784.0) * k5
                       + (float)(11.0 / 84.0) * k6);
        }
        if (lane < 16) {
            ztraj[(l + 1) * 16 + lane] = z;
            zdiff[l * 16 + lane] = (z - zstart) / dt;
        }
    }
}

// ---------------------------------------------------------------------------
// Decoder: fused 3-layer MLP over 51200 rows. M-tile=16, 256 threads,
// thread micro-tile 2 rows x 16 cols. g1/g2 share one LDS buffer (~34 KB).
// (unchanged)
// ---------------------------------------------------------------------------
#define GS 516   // padded LDS stride for the 16x512 activation tile

__global__ __launch_bounds__(256, 2) void dec_kernel(
    const float* __restrict__ ztr,
    const float* __restrict__ w1, const float* __restrict__ b1,
    const float* __restrict__ w2, const float* __restrict__ b2,
    const float* __restrict__ w3, const float* __restrict__ b3,
    float* __restrict__ xhat)
{
    __shared__ __align__(16) float zt[16 * 17];
    __shared__ __align__(16) float g[16 * GS];

    const int t    = threadIdx.x;
    const int blk  = blockIdx.x;
    const int tr   = t >> 5;         // 0..7
    const int tc   = t & 31;         // 0..31
    const int row0 = blk * 16;
    const int r0   = 2 * tr;

    {
        int r = t >> 4, dd = t & 15;
        zt[r * 17 + dd] = ztr[(row0 + r) * 16 + dd];
    }
    __syncthreads();

    // Phase A: g1 = relu(z @ w1 + b1), K=16
    {
        float acc[2][16];
#pragma unroll
        for (int p = 0; p < 2; ++p)
#pragma unroll
            for (int i = 0; i < 16; ++i) acc[p][i] = 0.0f;

#pragma unroll
        for (int k = 0; k < 16; ++k) {
            float a0 = zt[(r0 + 0) * 17 + k];
            float a1 = zt[(r0 + 1) * 17 + k];
            const float4* wr = (const float4*)(w1 + k * 512 + 16 * tc);
#pragma unroll
            for (int u = 0; u < 4; ++u) {
                float4 wv = wr[u];
                acc[0][4 * u + 0] = fmaf(a0, wv.x, acc[0][4 * u + 0]);
                acc[0][4 * u + 1] = fmaf(a0, wv.y, acc[0][4 * u + 1]);
                acc[0][4 * u + 2] = fmaf(a0, wv.z, acc[0][4 * u + 2]);
                acc[0][4 * u + 3] = fmaf(a0, wv.w, acc[0][4 * u + 3]);
                acc[1][4 * u + 0] = fmaf(a1, wv.x, acc[1][4 * u + 0]);
                acc[1][4 * u + 1] = fmaf(a1, wv.y, acc[1][4 * u + 1]);
                acc[1][4 * u + 2] = fmaf(a1, wv.z, acc[1][4 * u + 2]);
                acc[1][4 * u + 3] = fmaf(a1, wv.w, acc[1][4 * u + 3]);
            }
        }
        const float4* bb = (const float4*)(b1 + 16 * tc);
#pragma unroll
        for (int u = 0; u < 4; ++u) {
            float4 bv = bb[u];
#pragma unroll
            for (int p = 0; p < 2; ++p) {
                g[(r0 + p) * GS + 16 * tc + 4 * u + 0] = fmaxf(acc[p][4 * u + 0] + bv.x, 0.0f);
                g[(r0 + p) * GS + 16 * tc + 4 * u + 1] = fmaxf(acc[p][4 * u + 1] + bv.y, 0.0f);
                g[(r0 + p) * GS + 16 * tc + 4 * u + 2] = fmaxf(acc[p][4 * u + 2] + bv.z, 0.0f);
                g[(r0 + p) * GS + 16 * tc + 4 * u + 3] = fmaxf(acc[p][4 * u + 3] + bv.w, 0.0f);
            }
        }
    }
    __syncthreads();

    // Phase B: g2 = relu(g1 @ w2 + b2), K=512
    {
        float accB[2][16];
#pragma unroll
        for (int p = 0; p < 2; ++p)
#pragma unroll
            for (int i = 0; i < 16; ++i) accB[p][i] = 0.0f;

        for (int k4 = 0; k4 < 128; ++k4) {
            float4 av0 = *(const float4*)&g[(r0 + 0) * GS + 4 * k4];
            float4 av1 = *(const float4*)&g[(r0 + 1) * GS + 4 * k4];
            float a0[4] = {av0.x, av0.y, av0.z, av0.w};
            float a1[4] = {av1.x, av1.y, av1.z, av1.w};
#pragma unroll
            for (int u = 0; u < 4; ++u) {
                const float4* wr = (const float4*)(w2 + (4 * k4 + u) * 512 + 16 * tc);
#pragma unroll
                for (int q = 0; q < 4; ++q) {
                    float4 wv = wr[q];
                    accB[0][4 * q + 0] = fmaf(a0[u], wv.x, accB[0][4 * q + 0]);
                    accB[0][4 * q + 1] = fmaf(a0[u], wv.y, accB[0][4 * q + 1]);
                    accB[0][4 * q + 2] = fmaf(a0[u], wv.z, accB[0][4 * q + 2]);
                    accB[0][4 * q + 3] = fmaf(a0[u], wv.w, accB[0][4 * q + 3]);
                    accB[1][4 * q + 0] = fmaf(a1[u], wv.x, accB[1][4 * q + 0]);
                    accB[1][4 * q + 1] = fmaf(a1[u], wv.y, accB[1][4 * q + 1]);
                    accB[1][4 * q + 2] = fmaf(a1[u], wv.z, accB[1][4 * q + 2]);
                    accB[1][4 * q + 3] = fmaf(a1[u], wv.w, accB[1][4 * q + 3]);
                }
            }
        }
        __syncthreads();   // everyone done reading g1
        const float4* bb = (const float4*)(b2 + 16 * tc);
#pragma unroll
        for (int u = 0; u < 4; ++u) {
            float4 bv = bb[u];
#pragma unroll
            for (int p = 0; p < 2; ++p) {
                g[(r0 + p) * GS + 16 * tc + 4 * u + 0] = fmaxf(accB[p][4 * u + 0] + bv.x, 0.0f);
                g[(r0 + p) * GS + 16 * tc + 4 * u + 1] = fmaxf(accB[p][4 * u + 1] + bv.y, 0.0f);
                g[(r0 + p) * GS + 16 * tc + 4 * u + 2] = fmaxf(accB[p][4 * u + 2] + bv.z, 0.0f);
                g[(r0 + p) * GS + 16 * tc + 4 * u + 3] = fmaxf(accB[p][4 * u + 3] + bv.w, 0.0f);
            }
        }
    }
    __syncthreads();

    // Phase C: xhat = g2 @ w3 + b3, N=256 (8 cols/thread), K=512
    {
        float accC[2][8];
#pragma unroll
        for (int p = 0; p < 2; ++p)
#pragma unroll
            for (int i = 0; i < 8; ++i) accC[p][i] = 0.0f;

        for (int k4 = 0; k4 < 128; ++k4) {
            float4 av0 = *(const float4*)&g[(r0 + 0) * GS + 4 * k4];
            float4 av1 = *(const float4*)&g[(r0 + 1) * GS + 4 * k4];
            float a0[4] = {av0.x, av0.y, av0.z, av0.w};
            float a1[4] = {av1.x, av1.y, av1.z, av1.w};
#pragma unroll
            for (int u = 0; u < 4; ++u) {
                const float4* wr = (const float4*)(w3 + (4 * k4 + u) * 256 + 8 * tc);
                float4 w0 = wr[0], w1v = wr[1];
                accC[0][0] = fmaf(a0[u], w0.x,  accC[0][0]);
                accC[0][1] = fmaf(a0[u], w0.y,  accC[0][1]);
                accC[0][2] = fmaf(a0[u], w0.z,  accC[0][2]);
                accC[0][3] = fmaf(a0[u], w0.w,  accC[0][3]);
                accC[0][4] = fmaf(a0[u], w1v.x, accC[0][4]);
                accC[0][5] = fmaf(a0[u], w1v.y, accC[0][5]);
                accC[0][6] = fmaf(a0[u], w1v.z, accC[0][6]);
                accC[0][7] = fmaf(a0[u], w1v.w, accC[0][7]);
                accC[1][0] = fmaf(a1[u], w0.x,  accC[1][0]);
                accC[1][1] = fmaf(a1[u], w0.y,  accC[1][1]);
                accC[1][2] = fmaf(a1[u], w0.z,  accC[1][2]);
                accC[1][3] = fmaf(a1[u], w0.w,  accC[1][3]);
                accC[1][4] = fmaf(a1[u], w1v.x, accC[1][4]);
                accC[1][5] = fmaf(a1[u], w1v.y, accC[1][5]);
                accC[1][6] = fmaf(a1[u], w1v.z, accC[1][6]);
                accC[1][7] = fmaf(a1[u], w1v.w, accC[1][7]);
            }
        }
        const float4* bb = (const float4*)(b3 + 8 * tc);
        float4 bv0 = bb[0], bv1 = bb[1];
#pragma unroll
        for (int p = 0; p < 2; ++p) {
            float4 o0 = make_float4(accC[p][0] + bv0.x, accC[p][1] + bv0.y,
                                    accC[p][2] + bv0.z, accC[p][3] + bv0.w);
            float4 o1 = make_float4(accC[p][4] + bv1.x, accC[p][5] + bv1.y,
                                    accC[p][6] + bv1.z, accC[p][7] + bv1.w);
            float* dst = xhat + (size_t)(row0 + r0 + p) * 256 + 8 * tc;
            *(float4*)(dst)     = o0;
            *(float4*)(dst + 4) = o1;
        }
    }
}

extern "C" void kernel_launch(void* const* d_in, const int* in_sizes, int n_in,
                              void* d_out, int out_size, void* d_ws, size_t ws_size,
                              hipStream_t stream) {
    const float* x_seq  = (const float*)d_in[0];
    const float* tvec   = (const float*)d_in[1];
    const float* eps    = (const float*)d_in[2];
    const float* enc_w1 = (const float*)d_in[3];
    const float* enc_b1 = (const float*)d_in[4];
    const float* enc_w2 = (const float*)d_in[5];
    const float* enc_b2 = (const float*)d_in[6];
    const float* enc_w3 = (const float*)d_in[7];
    const float* enc_b3 = (const float*)d_in[8];
    const float* mu_w   = (const float*)d_in[9];
    const float* mu_b   = (const float*)d_in[10];
    const float* lv_w   = (const float*)d_in[11];
    const float* lv_b   = (const float*)d_in[12];
    const float* ode_w1 = (const float*)d_in[13];
    const float* ode_b1 = (const float*)d_in[14];
    const float* ode_w2 = (const float*)d_in[15];
    const float* ode_b2 = (const float*)d_in[16];
    const float* ode_w3 = (const float*)d_in[17];
    const float* ode_b3 = (const float*)d_in[18];
    const float* ln_g   = (const float*)d_in[19];
    const float* ln_b   = (const float*)d_in[20];
    const float* dec_w1 = (const float*)d_in[21];
    const float* dec_b1 = (const float*)d_in[22];
    const float* dec_w2 = (const float*)d_in[23];
    const float* dec_b2 = (const float*)d_in[24];
    const float* dec_w3 = (const float*)d_in[25];
    const float* dec_b3 = (const float*)d_in[26];
    float* out = (float*)d_out;

    enc_kernel<<<256, 256, 0, stream>>>(x_seq, eps, enc_w1, enc_b1, enc_w2, enc_b2,
                                        enc_w3, enc_b3, mu_w, mu_b, lv_w, lv_b, out);
    ode_kernel<<<256, 64, 0, stream>>>(tvec, ode_w1, ode_b1, ode_w2, ode_b2,
                                       ode_w3, ode_b3, ln_g, ln_b, out);
    dec_kernel<<<3200, 256, 0, stream>>>(out + OFF_ZT, dec_w1, dec_b1, dec_w2, dec_b2,
                                         dec_w3, dec_b3, out);
}

// Round 2
// 11778.620 us; speedup vs baseline: 4.1598x; 4.1598x over previous
//
#include <hip/hip_runtime.h>

// Output layout (flat f32, reference return order):
//   xhat  : B*L*N   = 13,107,200  @ 0
//   mu    : B*D     =      4,096  @ 13,107,200
//   logvar: B*D     =      4,096  @ 13,111,296
//   z_traj: B*L*D   =    819,200  @ 13,115,392
//   zdiff : B*(L-1)*D =  815,104  @ 13,934,592
#define OFF_MU   13107200
#define OFF_LV   13111296
#define OFF_ZT   13115392
#define OFF_ZD   13934592

typedef float v2f __attribute__((ext_vector_type(2)));

__device__ __forceinline__ float silu_f(float x) {
    return x / (1.0f + __expf(-x));
}

__device__ __forceinline__ v2f fma2(v2f a, v2f b, v2f c) {
    return __builtin_elementwise_fma(a, b, c);
}

// x + dpp_move(x) with compile-time DPP control. VALU-latency cross-lane.
template <int CTRL>
__device__ __forceinline__ float dppadd(float x) {
    int y = __builtin_amdgcn_update_dpp(0, __float_as_int(x), CTRL, 0xF, 0xF, true);
    return x + __int_as_float(y);
}

// Sum of x over each 16-lane row (values replicated per row afterwards).
// xor1 = quad_perm[1,0,3,2]=0xB1; xor2 = quad_perm[2,3,0,1]=0x4E;
// xor4 == row_half_mirror (0x141) once quad-uniform; xor8 == row_mirror (0x140)
// once 8-uniform.
__device__ __forceinline__ float sum16_dpp(float x) {
    x = dppadd<0xB1>(x);
    x = dppadd<0x4E>(x);
    x = dppadd<0x141>(x);
    x = dppadd<0x140>(x);
    return x;
}

// ---------------------------------------------------------------------------
// Encoder: one block per batch row. x0(256) -> 512 -> 256 -> 128 -> mu/lv(16)
// (unchanged — negligible cost)
// ---------------------------------------------------------------------------
__global__ __launch_bounds__(256) void enc_kernel(
    const float* __restrict__ xseq, const float* __restrict__ eps,
    const float* __restrict__ w1, const float* __restrict__ b1,
    const float* __restrict__ w2, const float* __restrict__ b2,
    const float* __restrict__ w3, const float* __restrict__ b3,
    const float* __restrict__ muw, const float* __restrict__ mub,
    const float* __restrict__ lvw, const float* __restrict__ lvb,
    float* __restrict__ out)
{
    __shared__ float xr[256];
    __shared__ float h1[512];
    __shared__ float h2[256];
    __shared__ float h3[128];

    const int t = threadIdx.x;
    const int b = blockIdx.x;

    xr[t] = xseq[b * (200 * 256) + t];
    __syncthreads();

    {
        float acc0 = b1[t], acc1 = b1[t + 256];
        for (int i = 0; i < 256; ++i) {
            float xv = xr[i];
            acc0 = fmaf(xv, w1[i * 512 + t],       acc0);
            acc1 = fmaf(xv, w1[i * 512 + t + 256], acc1);
        }
        h1[t]       = fmaxf(acc0, 0.0f);
        h1[t + 256] = fmaxf(acc1, 0.0f);
    }
    __syncthreads();

    {
        float acc = b2[t];
        for (int i = 0; i < 512; ++i) acc = fmaf(h1[i], w2[i * 256 + t], acc);
        h2[t] = fmaxf(acc, 0.0f);
    }
    __syncthreads();

    if (t < 128) {
        float acc = b3[t];
        for (int i = 0; i < 256; ++i) acc = fmaf(h2[i], w3[i * 128 + t], acc);
        h3[t] = fmaxf(acc, 0.0f);
    }
    __syncthreads();

    if (t < 16) {
        float mu = mub[t], lv = lvb[t];
        for (int i = 0; i < 128; ++i) {
            float hv = h3[i];
            mu = fmaf(hv, muw[i * 16 + t], mu);
            lv = fmaf(hv, lvw[i * 16 + t], lv);
        }
        out[OFF_MU + b * 16 + t] = mu;
        out[OFF_LV + b * 16 + t] = lv;
        float z0 = mu + __expf(0.5f * lv) * eps[b * 16 + t];
        out[OFF_ZT + b * 3200 + t] = z0;
    }
}

// ---------------------------------------------------------------------------
// ODE integrator v3: ONE WAVE per batch element, spill-free by construction.
//   - per-lane columns (lane, lane+64); all products natural v_pk_fma_f32
//     via K-pair packing ({even-k, odd-k} in one v2f).
//   - w2 split: k-pairs 0..KREG-1 in VGPRs (2*KREG v2f = 4*KREG regs),
//     k-pairs KREG..63 in LDS (contiguous ds_read_b64, conflict-free).
//   - z/k state replicated x4 (d = lane&15); zarg broadcast via tiny LDS row.
//   - LN 16-wide sums via DPP (quad_perm/mirror), ~8 VALU ops each.
//   - L3 4-way K-split reduced through a 64-float LDS partial buffer.
// VGPR budget ~215 (w1 32 + w2 96 + w3 32 + state/temps) < 256: no scratch.
// ---------------------------------------------------------------------------
#define KREG 24   // k-pairs of w2 kept in registers per column

__global__ __launch_bounds__(64, 1) void ode_kernel(
    const float* __restrict__ tvec,
    const float* __restrict__ ow1, const float* __restrict__ ob1,
    const float* __restrict__ ow2, const float* __restrict__ ob2,
    const float* __restrict__ ow3, const float* __restrict__ ob3,
    const float* __restrict__ lng, const float* __restrict__ lnb,
    float* __restrict__ out)
{
    __shared__ __align__(16) float zs[64];
    __shared__ __align__(16) float a1s[128];
    __shared__ __align__(16) float a2s[128];
    __shared__ __align__(16) float p3[64];
    __shared__ __align__(16) v2f  w2l[(64 - KREG) * 128];   // 40 KB

    const int lane = threadIdx.x;
    const int b    = blockIdx.x;
    const int d    = lane & 15;      // owned z-dim (replicated x4)
    const int g    = lane >> 4;      // replication group / L3 K-chunk
    const int l64  = lane + 64;

    // ---- stage w2 k-pairs KREG..63 into LDS (coalesced reads, one-time) ---
    for (int i = lane; i < (64 - KREG) * 128; i += 64) {
        int kp = KREG + (i >> 7);
        int c  = i & 127;
        v2f val = { ow2[(2 * kp) * 128 + c], ow2[(2 * kp + 1) * 128 + c] };
        w2l[i] = val;
    }

    // ---- register-resident weights (K-pair packed) ------------------------
    v2f w1r0[8], w1r1[8];
#pragma unroll
    for (int q = 0; q < 8; ++q) {
        v2f t0 = { ow1[(2 * q) * 128 + lane], ow1[(2 * q + 1) * 128 + lane] };
        v2f t1 = { ow1[(2 * q) * 128 + l64],  ow1[(2 * q + 1) * 128 + l64] };
        w1r0[q] = t0;
        w1r1[q] = t1;
    }
    v2f w2r0[KREG], w2r1[KREG];
#pragma unroll
    for (int q = 0; q < KREG; ++q) {
        v2f t0 = { ow2[(2 * q) * 128 + lane], ow2[(2 * q + 1) * 128 + lane] };
        v2f t1 = { ow2[(2 * q) * 128 + l64],  ow2[(2 * q + 1) * 128 + l64] };
        w2r0[q] = t0;
        w2r1[q] = t1;
    }
    v2f w3r[16];   // K-chunk g (32 wide), stored in bank-staggered read order
#pragma unroll
    for (int qq = 0; qq < 8; ++qq) {
        int qsel = (qq + 2 * g) & 7;
        int k0   = 32 * g + 4 * qsel;
        v2f t0 = { ow3[(k0 + 0) * 16 + d], ow3[(k0 + 1) * 16 + d] };
        v2f t1 = { ow3[(k0 + 2) * 16 + d], ow3[(k0 + 3) * 16 + d] };
        w3r[2 * qq]     = t0;
        w3r[2 * qq + 1] = t1;
    }
    const float b1j0 = ob1[lane], b1j1 = ob1[l64];
    const float b2j0 = ob2[lane], b2j1 = ob2[l64];
    const float b3d  = ob3[d];
    const float lngd = lng[d], lnbd = lnb[d];

    float* ztraj = out + OFF_ZT + b * 3200;   // [200][16]
    float* zdiff = out + OFF_ZD + b * 3184;   // [199][16]

    __syncthreads();                          // w2l staged

    float z = ztraj[d];                       // z0, replicated x4

    // one evaluation of f(za); za = zarg[d] per lane (replicated x4).
    auto feval = [&](float za) -> float {
        // broadcast zarg: each group writes its own 16-slot row, reads it back
        zs[lane] = za;
        __syncthreads();
        const float4* zv4 = (const float4*)(zs + 16 * g);

        // L1: 2 cols/lane, K=16 as 8 pairs
        v2f acc0 = {0.0f, 0.0f}, acc1 = {0.0f, 0.0f};
#pragma unroll
        for (int q4 = 0; q4 < 4; ++q4) {
            float4 av = zv4[q4];
            v2f plo = { av.x, av.y };
            v2f phi = { av.z, av.w };
            acc0 = fma2(plo, w1r0[2 * q4],     acc0);
            acc1 = fma2(plo, w1r1[2 * q4],     acc1);
            acc0 = fma2(phi, w1r0[2 * q4 + 1], acc0);
            acc1 = fma2(phi, w1r1[2 * q4 + 1], acc1);
        }
        a1s[lane] = silu_f(acc0.x + acc0.y + b1j0);
        a1s[l64]  = silu_f(acc1.x + acc1.y + b1j1);
        __syncthreads();

        // L2: 2 cols/lane, K=128 as 64 pairs; a1 via broadcast b128 reads;
        // pairs < KREG from registers, rest from LDS (contiguous b64).
        v2f accA = {0.0f, 0.0f}, accB = {0.0f, 0.0f};
        const float4* a14 = (const float4*)a1s;
#pragma unroll
        for (int q4 = 0; q4 < 32; ++q4) {
            float4 av = a14[q4];
            v2f plo = { av.x, av.y };
            v2f phi = { av.z, av.w };
            const int kp0 = 2 * q4, kp1 = 2 * q4 + 1;
            if (kp0 < KREG) {
                accA = fma2(plo, w2r0[kp0], accA);
                accB = fma2(plo, w2r1[kp0], accB);
            } else {
                accA = fma2(plo, w2l[(kp0 - KREG) * 128 + lane], accA);
                accB = fma2(plo, w2l[(kp0 - KREG) * 128 + l64],  accB);
            }
            if (kp1 < KREG) {
                accA = fma2(phi, w2r0[kp1], accA);
                accB = fma2(phi, w2r1[kp1], accB);
            } else {
                accA = fma2(phi, w2l[(kp1 - KREG) * 128 + lane], accA);
                accB = fma2(phi, w2l[(kp1 - KREG) * 128 + l64],  accB);
            }
        }
        a2s[lane] = silu_f(accA.x + accA.y + b2j0);
        a2s[l64]  = silu_f(accB.x + accB.y + b2j1);
        __syncthreads();

        // L3: output d, K-chunk g (32 wide), bank-staggered b128 reads
        v2f pp = {0.0f, 0.0f};
        const float4* a24 = (const float4*)(a2s + 32 * g);
#pragma unroll
        for (int qq = 0; qq < 8; ++qq) {
            int qsel = (qq + 2 * g) & 7;
            float4 av = a24[qsel];
            v2f plo = { av.x, av.y };
            v2f phi = { av.z, av.w };
            pp = fma2(plo, w3r[2 * qq],     pp);
            pp = fma2(phi, w3r[2 * qq + 1], pp);
        }
        // combine 4 K-chunks through LDS partials
        p3[4 * d + g] = pp.x + pp.y;
        __syncthreads();
        float4 pv = *(const float4*)(p3 + 4 * d);   // broadcast per d, 2-way ok
        float dz = b3d + pv.x + pv.y + pv.z + pv.w;

        // LayerNorm over d=0..15 via DPP row sums (replicated result)
        float m  = sum16_dpp(dz) * 0.0625f;
        float df = dz - m;
        float v  = sum16_dpp(df * df) * 0.0625f;
        return df * rsqrtf(v + 1e-5f) * lngd + lnbd;
    };

    for (int l = 0; l < 199; ++l) {
        const float dt = tvec[l + 1] - tvec[l];
        const float h  = dt * 0.125f;          // dt / K, K=8 (exact)
        const float zstart = z;
        for (int s = 0; s < 8; ++s) {
            float k1 = feval(z);
            float k2 = feval(z + h * (k1 * (float)(1.0 / 5.0)));
            float k3 = feval(z + h * ((float)(3.0 / 40.0) * k1 + (float)(9.0 / 40.0) * k2));
            float k4 = feval(z + h * ((float)(44.0 / 45.0) * k1 - (float)(56.0 / 15.0) * k2
                                    + (float)(32.0 / 9.0) * k3));
            float k5 = feval(z + h * ((float)(19372.0 / 6561.0) * k1 - (float)(25360.0 / 2187.0) * k2
                                    + (float)(64448.0 / 6561.0) * k3 - (float)(212.0 / 729.0) * k4));
            float k6 = feval(z + h * ((float)(9017.0 / 3168.0) * k1 - (float)(355.0 / 33.0) * k2
                                    + (float)(46732.0 / 5247.0) * k3 + (float)(49.0 / 176.0) * k4
                                    - (float)(5103.0 / 18656.0) * k5));
            z = z + h * ((float)(35.0 / 384.0) * k1 + (float)(500.0 / 1113.0) * k3
                       + (float)(125.0 / 192.0) * k4 - (float)(2187.0 / 6784.0) * k5
                       + (float)(11.0 / 84.0) * k6);
        }
        if (lane < 16) {
            ztraj[(l + 1) * 16 + lane] = z;
            zdiff[l * 16 + lane] = (z - zstart) / dt;
        }
    }
}

// ---------------------------------------------------------------------------
// Decoder: fused 3-layer MLP over 51200 rows. (unchanged)
// ---------------------------------------------------------------------------
#define GS 516   // padded LDS stride for the 16x512 activation tile

__global__ __launch_bounds__(256, 2) void dec_kernel(
    const float* __restrict__ ztr,
    const float* __restrict__ w1, const float* __restrict__ b1,
    const float* __restrict__ w2, const float* __restrict__ b2,
    const float* __restrict__ w3, const float* __restrict__ b3,
    float* __restrict__ xhat)
{
    __shared__ __align__(16) float zt[16 * 17];
    __shared__ __align__(16) float g[16 * GS];

    const int t    = threadIdx.x;
    const int blk  = blockIdx.x;
    const int tr   = t >> 5;
    const int tc   = t & 31;
    const int row0 = blk * 16;
    const int r0   = 2 * tr;

    {
        int r = t >> 4, dd = t & 15;
        zt[r * 17 + dd] = ztr[(row0 + r) * 16 + dd];
    }
    __syncthreads();

    // Phase A: g1 = relu(z @ w1 + b1), K=16
    {
        float acc[2][16];
#pragma unroll
        for (int p = 0; p < 2; ++p)
#pragma unroll
            for (int i = 0; i < 16; ++i) acc[p][i] = 0.0f;

#pragma unroll
        for (int k = 0; k < 16; ++k) {
            float a0 = zt[(r0 + 0) * 17 + k];
            float a1 = zt[(r0 + 1) * 17 + k];
            const float4* wr = (const float4*)(w1 + k * 512 + 16 * tc);
#pragma unroll
            for (int u = 0; u < 4; ++u) {
                float4 wv = wr[u];
                acc[0][4 * u + 0] = fmaf(a0, wv.x, acc[0][4 * u + 0]);
                acc[0][4 * u + 1] = fmaf(a0, wv.y, acc[0][4 * u + 1]);
                acc[0][4 * u + 2] = fmaf(a0, wv.z, acc[0][4 * u + 2]);
                acc[0][4 * u + 3] = fmaf(a0, wv.w, acc[0][4 * u + 3]);
                acc[1][4 * u + 0] = fmaf(a1, wv.x, acc[1][4 * u + 0]);
                acc[1][4 * u + 1] = fmaf(a1, wv.y, acc[1][4 * u + 1]);
                acc[1][4 * u + 2] = fmaf(a1, wv.z, acc[1][4 * u + 2]);
                acc[1][4 * u + 3] = fmaf(a1, wv.w, acc[1][4 * u + 3]);
            }
        }
        const float4* bb = (const float4*)(b1 + 16 * tc);
#pragma unroll
        for (int u = 0; u < 4; ++u) {
            float4 bv = bb[u];
#pragma unroll
            for (int p = 0; p < 2; ++p) {
                g[(r0 + p) * GS + 16 * tc + 4 * u + 0] = fmaxf(acc[p][4 * u + 0] + bv.x, 0.0f);
                g[(r0 + p) * GS + 16 * tc + 4 * u + 1] = fmaxf(acc[p][4 * u + 1] + bv.y, 0.0f);
                g[(r0 + p) * GS + 16 * tc + 4 * u + 2] = fmaxf(acc[p][4 * u + 2] + bv.z, 0.0f);
                g[(r0 + p) * GS + 16 * tc + 4 * u + 3] = fmaxf(acc[p][4 * u + 3] + bv.w, 0.0f);
            }
        }
    }
    __syncthreads();

    // Phase B: g2 = relu(g1 @ w2 + b2), K=512
    {
        float accB[2][16];
#pragma unroll
        for (int p = 0; p < 2; ++p)
#pragma unroll
            for (int i = 0; i < 16; ++i) accB[p][i] = 0.0f;

        for (int k4 = 0; k4 < 128; ++k4) {
            float4 av0 = *(const float4*)&g[(r0 + 0) * GS + 4 * k4];
            float4 av1 = *(const float4*)&g[(r0 + 1) * GS + 4 * k4];
            float a0[4] = {av0.x, av0.y, av0.z, av0.w};
            float a1[4] = {av1.x, av1.y, av1.z, av1.w};
#pragma unroll
            for (int u = 0; u < 4; ++u) {
                const float4* wr = (const float4*)(w2 + (4 * k4 + u) * 512 + 16 * tc);
#pragma unroll
                for (int q = 0; q < 4; ++q) {
                    float4 wv = wr[q];
                    accB[0][4 * q + 0] = fmaf(a0[u], wv.x, accB[0][4 * q + 0]);
                    accB[0][4 * q + 1] = fmaf(a0[u], wv.y, accB[0][4 * q + 1]);
                    accB[0][4 * q + 2] = fmaf(a0[u], wv.z, accB[0][4 * q + 2]);
                    accB[0][4 * q + 3] = fmaf(a0[u], wv.w, accB[0][4 * q + 3]);
                    accB[1][4 * q + 0] = fmaf(a1[u], wv.x, accB[1][4 * q + 0]);
                    accB[1][4 * q + 1] = fmaf(a1[u], wv.y, accB[1][4 * q + 1]);
                    accB[1][4 * q + 2] = fmaf(a1[u], wv.z, accB[1][4 * q + 2]);
                    accB[1][4 * q + 3] = fmaf(a1[u], wv.w, accB[1][4 * q + 3]);
                }
            }
        }
        __syncthreads();
        const float4* bb = (const float4*)(b2 + 16 * tc);
#pragma unroll
        for (int u = 0; u < 4; ++u) {
            float4 bv = bb[u];
#pragma unroll
            for (int p = 0; p < 2; ++p) {
                g[(r0 + p) * GS + 16 * tc + 4 * u + 0] = fmaxf(accB[p][4 * u + 0] + bv.x, 0.0f);
                g[(r0 + p) * GS + 16 * tc + 4 * u + 1] = fmaxf(accB[p][4 * u + 1] + bv.y, 0.0f);
                g[(r0 + p) * GS + 16 * tc + 4 * u + 2] = fmaxf(accB[p][4 * u + 2] + bv.z, 0.0f);
                g[(r0 + p) * GS + 16 * tc + 4 * u + 3] = fmaxf(accB[p][4 * u + 3] + bv.w, 0.0f);
            }
        }
    }
    __syncthreads();

    // Phase C: xhat = g2 @ w3 + b3, N=256 (8 cols/thread), K=512
    {
        float accC[2][8];
#pragma unroll
        for (int p = 0; p < 2; ++p)
#pragma unroll
            for (int i = 0; i < 8; ++i) accC[p][i] = 0.0f;

        for (int k4 = 0; k4 < 128; ++k4) {
            float4 av0 = *(const float4*)&g[(r0 + 0) * GS + 4 * k4];
            float4 av1 = *(const float4*)&g[(r0 + 1) * GS + 4 * k4];
            float a0[4] = {av0.x, av0.y, av0.z, av0.w};
            float a1[4] = {av1.x, av1.y, av1.z, av1.w};
#pragma unroll
            for (int u = 0; u < 4; ++u) {
                const float4* wr = (const float4*)(w3 + (4 * k4 + u) * 256 + 8 * tc);
                float4 w0 = wr[0], w1v = wr[1];
                accC[0][0] = fmaf(a0[u], w0.x,  accC[0][0]);
                accC[0][1] = fmaf(a0[u], w0.y,  accC[0][1]);
                accC[0][2] = fmaf(a0[u], w0.z,  accC[0][2]);
                accC[0][3] = fmaf(a0[u], w0.w,  accC[0][3]);
                accC[0][4] = fmaf(a0[u], w1v.x, accC[0][4]);
                accC[0][5] = fmaf(a0[u], w1v.y, accC[0][5]);
                accC[0][6] = fmaf(a0[u], w1v.z, accC[0][6]);
                accC[0][7] = fmaf(a0[u], w1v.w, accC[0][7]);
                accC[1][0] = fmaf(a1[u], w0.x,  accC[1][0]);
                accC[1][1] = fmaf(a1[u], w0.y,  accC[1][1]);
                accC[1][2] = fmaf(a1[u], w0.z,  accC[1][2]);
                accC[1][3] = fmaf(a1[u], w0.w,  accC[1][3]);
                accC[1][4] = fmaf(a1[u], w1v.x, accC[1][4]);
                accC[1][5] = fmaf(a1[u], w1v.y, accC[1][5]);
                accC[1][6] = fmaf(a1[u], w1v.z, accC[1][6]);
                accC[1][7] = fmaf(a1[u], w1v.w, accC[1][7]);
            }
        }
        const float4* bb = (const float4*)(b3 + 8 * tc);
        float4 bv0 = bb[0], bv1 = bb[1];
#pragma unroll
        for (int p = 0; p < 2; ++p) {
            float4 o0 = make_float4(accC[p][0] + bv0.x, accC[p][1] + bv0.y,
                                    accC[p][2] + bv0.z, accC[p][3] + bv0.w);
            float4 o1 = make_float4(accC[p][4] + bv1.x, accC[p][5] + bv1.y,
                                    accC[p][6] + bv1.z, accC[p][7] + bv1.w);
            float* dst = xhat + (size_t)(row0 + r0 + p) * 256 + 8 * tc;
            *(float4*)(dst)     = o0;
            *(float4*)(dst + 4) = o1;
        }
    }
}

extern "C" void kernel_launch(void* const* d_in, const int* in_sizes, int n_in,
                              void* d_out, int out_size, void* d_ws, size_t ws_size,
                              hipStream_t stream) {
    const float* x_seq  = (const float*)d_in[0];
    const float* tvec   = (const float*)d_in[1];
    const float* eps    = (const float*)d_in[2];
    const float* enc_w1 = (const float*)d_in[3];
    const float* enc_b1 = (const float*)d_in[4];
    const float* enc_w2 = (const float*)d_in[5];
    const float* enc_b2 = (const float*)d_in[6];
    const float* enc_w3 = (const float*)d_in[7];
    const float* enc_b3 = (const float*)d_in[8];
    const float* mu_w   = (const float*)d_in[9];
    const float* mu_b   = (const float*)d_in[10];
    const float* lv_w   = (const float*)d_in[11];
    const float* lv_b   = (const float*)d_in[12];
    const float* ode_w1 = (const float*)d_in[13];
    const float* ode_b1 = (const float*)d_in[14];
    const float* ode_w2 = (const float*)d_in[15];
    const float* ode_b2 = (const float*)d_in[16];
    const float* ode_w3 = (const float*)d_in[17];
    const float* ode_b3 = (const float*)d_in[18];
    const float* ln_g   = (const float*)d_in[19];
    const float* ln_b   = (const float*)d_in[20];
    const float* dec_w1 = (const float*)d_in[21];
    const float* dec_b1 = (const float*)d_in[22];
    const float* dec_w2 = (const float*)d_in[23];
    const float* dec_b2 = (const float*)d_in[24];
    const float* dec_w3 = (const float*)d_in[25];
    const float* dec_b3 = (const float*)d_in[26];
    float* out = (float*)d_out;

    enc_kernel<<<256, 256, 0, stream>>>(x_seq, eps, enc_w1, enc_b1, enc_w2, enc_b2,
                                        enc_w3, enc_b3, mu_w, mu_b, lv_w, lv_b, out);
    ode_kernel<<<256, 64, 0, stream>>>(tvec, ode_w1, ode_b1, ode_w2, ode_b2,
                                       ode_w3, ode_b3, ln_g, ln_b, out);
    dec_kernel<<<3200, 256, 0, stream>>>(out + OFF_ZT, dec_w1, dec_b1, dec_w2, dec_b2,
                                         dec_w3, dec_b3, out);
}

// Round 3
// 11738.099 us; speedup vs baseline: 4.1741x; 1.0035x over previous
//
#include <hip/hip_runtime.h>

// Output layout (flat f32, reference return order):
//   xhat  : B*L*N   = 13,107,200  @ 0
//   mu    : B*D     =      4,096  @ 13,107,200
//   logvar: B*D     =      4,096  @ 13,111,296
//   z_traj: B*L*D   =    819,200  @ 13,115,392
//   zdiff : B*(L-1)*D =  815,104  @ 13,934,592
#define OFF_MU   13107200
#define OFF_LV   13111296
#define OFF_ZT   13115392
#define OFF_ZD   13934592

typedef float v2f __attribute__((ext_vector_type(2)));

__device__ __forceinline__ float silu_f(float x) {
    return x / (1.0f + __expf(-x));
}

__device__ __forceinline__ v2f fma2(v2f a, v2f b, v2f c) {
    return __builtin_elementwise_fma(a, b, c);
}

// x + dpp_move(x) with compile-time DPP control. VALU-latency cross-lane.
template <int CTRL>
__device__ __forceinline__ float dppadd(float x) {
    int y = __builtin_amdgcn_update_dpp(0, __float_as_int(x), CTRL, 0xF, 0xF, true);
    return x + __int_as_float(y);
}

// Sum of x over each 16-lane row (values replicated per row afterwards).
__device__ __forceinline__ float sum16_dpp(float x) {
    x = dppadd<0xB1>(x);    // quad_perm xor1
    x = dppadd<0x4E>(x);    // quad_perm xor2
    x = dppadd<0x141>(x);   // row_half_mirror (xor4 once quad-uniform)
    x = dppadd<0x140>(x);   // row_mirror (xor8 once 8-uniform)
    return x;
}

// ---------------------------------------------------------------------------
// Encoder: one block per batch row. x0(256) -> 512 -> 256 -> 128 -> mu/lv(16)
// (unchanged — negligible cost)
// ---------------------------------------------------------------------------
__global__ __launch_bounds__(256) void enc_kernel(
    const float* __restrict__ xseq, const float* __restrict__ eps,
    const float* __restrict__ w1, const float* __restrict__ b1,
    const float* __restrict__ w2, const float* __restrict__ b2,
    const float* __restrict__ w3, const float* __restrict__ b3,
    const float* __restrict__ muw, const float* __restrict__ mub,
    const float* __restrict__ lvw, const float* __restrict__ lvb,
    float* __restrict__ out)
{
    __shared__ float xr[256];
    __shared__ float h1[512];
    __shared__ float h2[256];
    __shared__ float h3[128];

    const int t = threadIdx.x;
    const int b = blockIdx.x;

    xr[t] = xseq[b * (200 * 256) + t];
    __syncthreads();

    {
        float acc0 = b1[t], acc1 = b1[t + 256];
        for (int i = 0; i < 256; ++i) {
            float xv = xr[i];
            acc0 = fmaf(xv, w1[i * 512 + t],       acc0);
            acc1 = fmaf(xv, w1[i * 512 + t + 256], acc1);
        }
        h1[t]       = fmaxf(acc0, 0.0f);
        h1[t + 256] = fmaxf(acc1, 0.0f);
    }
    __syncthreads();

    {
        float acc = b2[t];
        for (int i = 0; i < 512; ++i) acc = fmaf(h1[i], w2[i * 256 + t], acc);
        h2[t] = fmaxf(acc, 0.0f);
    }
    __syncthreads();

    if (t < 128) {
        float acc = b3[t];
        for (int i = 0; i < 256; ++i) acc = fmaf(h2[i], w3[i * 128 + t], acc);
        h3[t] = fmaxf(acc, 0.0f);
    }
    __syncthreads();

    if (t < 16) {
        float mu = mub[t], lv = lvb[t];
        for (int i = 0; i < 128; ++i) {
            float hv = h3[i];
            mu = fmaf(hv, muw[i * 16 + t], mu);
            lv = fmaf(hv, lvw[i * 16 + t], lv);
        }
        out[OFF_MU + b * 16 + t] = mu;
        out[OFF_LV + b * 16 + t] = lv;
        float z0 = mu + __expf(0.5f * lv) * eps[b * 16 + t];
        out[OFF_ZT + b * 3200 + t] = z0;
    }
}

// ---------------------------------------------------------------------------
// ODE integrator v4: ONE WAVE per batch element.
//   v3 post-mortem: compiler rematerialized weight "registers" as per-feval
//   global reloads (VGPR_Count=132 < 160 intended). Fix: volatile loads —
//   cannot be re-executed, so values must stay resident.
//   Also: w2 LDS tail packed as float4 (half the ds_read instrs), and the
//   L3 K-chunk combine uses shfl_xor instead of an LDS round trip.
// ---------------------------------------------------------------------------
#define KREG 24   // k-pairs of w2 kept in registers per column

__global__ __launch_bounds__(64, 1) void ode_kernel(
    const float* __restrict__ tvec,
    const float* __restrict__ ow1, const float* __restrict__ ob1,
    const float* __restrict__ ow2, const float* __restrict__ ob2,
    const float* __restrict__ ow3, const float* __restrict__ ob3,
    const float* __restrict__ lng, const float* __restrict__ lnb,
    float* __restrict__ out)
{
    __shared__ __align__(16) float  zs[64];
    __shared__ __align__(16) float  a1s[128];
    __shared__ __align__(16) float  a2s[128];
    __shared__ __align__(16) float4 w2l[(64 - KREG) * 64];   // 40 KB, packed

    const int lane = threadIdx.x;
    const int b    = blockIdx.x;
    const int d    = lane & 15;      // owned z-dim (replicated x4)
    const int g    = lane >> 4;      // replication group / L3 K-chunk
    const int l64  = lane + 64;

    // ---- stage w2 k-pairs KREG..63 into LDS, packed {k0,k1}x{j,j+64} ------
    // w2l[(kp-KREG)*64 + j] = { w2[2kp][j], w2[2kp+1][j], w2[2kp][j+64], w2[2kp+1][j+64] }
    for (int kp = KREG; kp < 64; ++kp) {
        float4 val;
        val.x = ow2[(2 * kp) * 128 + lane];
        val.y = ow2[(2 * kp + 1) * 128 + lane];
        val.z = ow2[(2 * kp) * 128 + l64];
        val.w = ow2[(2 * kp + 1) * 128 + l64];
        w2l[(kp - KREG) * 64 + lane] = val;
    }

    // ---- register-resident weights via VOLATILE loads (no remat possible) -
    const volatile float* vw1 = ow1;
    const volatile float* vw2 = ow2;
    const volatile float* vw3 = ow3;

    v2f w1r0[8], w1r1[8];
#pragma unroll
    for (int q = 0; q < 8; ++q) {
        v2f t0 = { vw1[(2 * q) * 128 + lane], vw1[(2 * q + 1) * 128 + lane] };
        v2f t1 = { vw1[(2 * q) * 128 + l64],  vw1[(2 * q + 1) * 128 + l64] };
        w1r0[q] = t0;
        w1r1[q] = t1;
    }
    v2f w2r0[KREG], w2r1[KREG];
#pragma unroll
    for (int q = 0; q < KREG; ++q) {
        v2f t0 = { vw2[(2 * q) * 128 + lane], vw2[(2 * q + 1) * 128 + lane] };
        v2f t1 = { vw2[(2 * q) * 128 + l64],  vw2[(2 * q + 1) * 128 + l64] };
        w2r0[q] = t0;
        w2r1[q] = t1;
    }
    v2f w3r[16];   // K-chunk g (32 wide), stored in bank-staggered read order
#pragma unroll
    for (int qq = 0; qq < 8; ++qq) {
        int qsel = (qq + 2 * g) & 7;
        int k0   = 32 * g + 4 * qsel;
        v2f t0 = { vw3[(k0 + 0) * 16 + d], vw3[(k0 + 1) * 16 + d] };
        v2f t1 = { vw3[(k0 + 2) * 16 + d], vw3[(k0 + 3) * 16 + d] };
        w3r[2 * qq]     = t0;
        w3r[2 * qq + 1] = t1;
    }
    const volatile float* vb1 = ob1;
    const volatile float* vb2 = ob2;
    const volatile float* vb3 = ob3;
    const volatile float* vlg = lng;
    const volatile float* vlb = lnb;
    const float b1j0 = vb1[lane], b1j1 = vb1[l64];
    const float b2j0 = vb2[lane], b2j1 = vb2[l64];
    const float b3d  = vb3[d];
    const float lngd = vlg[d], lnbd = vlb[d];

    float* ztraj = out + OFF_ZT + b * 3200;   // [200][16]
    float* zdiff = out + OFF_ZD + b * 3184;   // [199][16]

    __syncthreads();                          // WG==wave: compiles to waitcnt

    float z = ztraj[d];                       // z0, replicated x4

    // one evaluation of f(za); za = zarg[d] per lane (replicated x4).
    auto feval = [&](float za) -> float {
        // broadcast zarg: each group writes its own 16-slot row, reads it back
        zs[lane] = za;
        __syncthreads();
        const float4* zv4 = (const float4*)(zs + 16 * g);

        // L1: 2 cols/lane, K=16 as 8 pairs
        v2f acc0 = {0.0f, 0.0f}, acc1 = {0.0f, 0.0f};
#pragma unroll
        for (int q4 = 0; q4 < 4; ++q4) {
            float4 av = zv4[q4];
            v2f plo = { av.x, av.y };
            v2f phi = { av.z, av.w };
            acc0 = fma2(plo, w1r0[2 * q4],     acc0);
            acc1 = fma2(plo, w1r1[2 * q4],     acc1);
            acc0 = fma2(phi, w1r0[2 * q4 + 1], acc0);
            acc1 = fma2(phi, w1r1[2 * q4 + 1], acc1);
        }
        a1s[lane] = silu_f(acc0.x + acc0.y + b1j0);
        a1s[l64]  = silu_f(acc1.x + acc1.y + b1j1);
        __syncthreads();

        // L2: 2 cols/lane, K=128 as 64 pairs; a1 via broadcast b128 reads;
        // pairs < KREG from registers, rest from packed LDS (one b128 each).
        v2f accA = {0.0f, 0.0f}, accB = {0.0f, 0.0f};
        const float4* a14 = (const float4*)a1s;
#pragma unroll
        for (int q4 = 0; q4 < 32; ++q4) {
            float4 av = a14[q4];
            v2f plo = { av.x, av.y };
            v2f phi = { av.z, av.w };
            const int kp0 = 2 * q4, kp1 = 2 * q4 + 1;
            if (kp0 < KREG) {
                accA = fma2(plo, w2r0[kp0], accA);
                accB = fma2(plo, w2r1[kp0], accB);
            } else {
                float4 wv = w2l[(kp0 - KREG) * 64 + lane];
                v2f wlo = { wv.x, wv.y };
                v2f whi = { wv.z, wv.w };
                accA = fma2(plo, wlo, accA);
                accB = fma2(plo, whi, accB);
            }
            if (kp1 < KREG) {
                accA = fma2(phi, w2r0[kp1], accA);
                accB = fma2(phi, w2r1[kp1], accB);
            } else {
                float4 wv = w2l[(kp1 - KREG) * 64 + lane];
                v2f wlo = { wv.x, wv.y };
                v2f whi = { wv.z, wv.w };
                accA = fma2(phi, wlo, accA);
                accB = fma2(phi, whi, accB);
            }
        }
        a2s[lane] = silu_f(accA.x + accA.y + b2j0);
        a2s[l64]  = silu_f(accB.x + accB.y + b2j1);
        __syncthreads();

        // L3: output d, K-chunk g (32 wide), bank-staggered b128 reads
        v2f pp = {0.0f, 0.0f};
        const float4* a24 = (const float4*)(a2s + 32 * g);
#pragma unroll
        for (int qq = 0; qq < 8; ++qq) {
            int qsel = (qq + 2 * g) & 7;
            float4 av = a24[qsel];
            v2f plo = { av.x, av.y };
            v2f phi = { av.z, av.w };
            pp = fma2(plo, w3r[2 * qq],     pp);
            pp = fma2(phi, w3r[2 * qq + 1], pp);
        }
        // combine 4 K-chunks across lane groups (xor16 then xor32)
        float pd = pp.x + pp.y;
        pd += __shfl_xor(pd, 16);
        pd += __shfl_xor(pd, 32);
        float dz = pd + b3d;

        // LayerNorm over d=0..15 via DPP row sums (replicated result)
        float m  = sum16_dpp(dz) * 0.0625f;
        float df = dz - m;
        float v  = sum16_dpp(df * df) * 0.0625f;
        return df * rsqrtf(v + 1e-5f) * lngd + lnbd;
    };

    for (int l = 0; l < 199; ++l) {
        const float dt = tvec[l + 1] - tvec[l];
        const float h  = dt * 0.125f;          // dt / K, K=8 (exact)
        const float zstart = z;
        for (int s = 0; s < 8; ++s) {
            float k1 = feval(z);
            float k2 = feval(z + h * (k1 * (float)(1.0 / 5.0)));
            float k3 = feval(z + h * ((float)(3.0 / 40.0) * k1 + (float)(9.0 / 40.0) * k2));
            float k4 = feval(z + h * ((float)(44.0 / 45.0) * k1 - (float)(56.0 / 15.0) * k2
                                    + (float)(32.0 / 9.0) * k3));
            float k5 = feval(z + h * ((float)(19372.0 / 6561.0) * k1 - (float)(25360.0 / 2187.0) * k2
                                    + (float)(64448.0 / 6561.0) * k3 - (float)(212.0 / 729.0) * k4));
            float k6 = feval(z + h * ((float)(9017.0 / 3168.0) * k1 - (float)(355.0 / 33.0) * k2
                                    + (float)(46732.0 / 5247.0) * k3 + (float)(49.0 / 176.0) * k4
                                    - (float)(5103.0 / 18656.0) * k5));
            z = z + h * ((float)(35.0 / 384.0) * k1 + (float)(500.0 / 1113.0) * k3
                       + (float)(125.0 / 192.0) * k4 - (float)(2187.0 / 6784.0) * k5
                       + (float)(11.0 / 84.0) * k6);
        }
        if (lane < 16) {
            ztraj[(l + 1) * 16 + lane] = z;
            zdiff[l * 16 + lane] = (z - zstart) / dt;
        }
    }
}

// ---------------------------------------------------------------------------
// Decoder: fused 3-layer MLP over 51200 rows. (unchanged)
// ---------------------------------------------------------------------------
#define GS 516   // padded LDS stride for the 16x512 activation tile

__global__ __launch_bounds__(256, 2) void dec_kernel(
    const float* __restrict__ ztr,
    const float* __restrict__ w1, const float* __restrict__ b1,
    const float* __restrict__ w2, const float* __restrict__ b2,
    const float* __restrict__ w3, const float* __restrict__ b3,
    float* __restrict__ xhat)
{
    __shared__ __align__(16) float zt[16 * 17];
    __shared__ __align__(16) float g[16 * GS];

    const int t    = threadIdx.x;
    const int blk  = blockIdx.x;
    const int tr   = t >> 5;
    const int tc   = t & 31;
    const int row0 = blk * 16;
    const int r0   = 2 * tr;

    {
        int r = t >> 4, dd = t & 15;
        zt[r * 17 + dd] = ztr[(row0 + r) * 16 + dd];
    }
    __syncthreads();

    // Phase A: g1 = relu(z @ w1 + b1), K=16
    {
        float acc[2][16];
#pragma unroll
        for (int p = 0; p < 2; ++p)
#pragma unroll
            for (int i = 0; i < 16; ++i) acc[p][i] = 0.0f;

#pragma unroll
        for (int k = 0; k < 16; ++k) {
            float a0 = zt[(r0 + 0) * 17 + k];
            float a1 = zt[(r0 + 1) * 17 + k];
            const float4* wr = (const float4*)(w1 + k * 512 + 16 * tc);
#pragma unroll
            for (int u = 0; u < 4; ++u) {
                float4 wv = wr[u];
                acc[0][4 * u + 0] = fmaf(a0, wv.x, acc[0][4 * u + 0]);
                acc[0][4 * u + 1] = fmaf(a0, wv.y, acc[0][4 * u + 1]);
                acc[0][4 * u + 2] = fmaf(a0, wv.z, acc[0][4 * u + 2]);
                acc[0][4 * u + 3] = fmaf(a0, wv.w, acc[0][4 * u + 3]);
                acc[1][4 * u + 0] = fmaf(a1, wv.x, acc[1][4 * u + 0]);
                acc[1][4 * u + 1] = fmaf(a1, wv.y, acc[1][4 * u + 1]);
                acc[1][4 * u + 2] = fmaf(a1, wv.z, acc[1][4 * u + 2]);
                acc[1][4 * u + 3] = fmaf(a1, wv.w, acc[1][4 * u + 3]);
            }
        }
        const float4* bb = (const float4*)(b1 + 16 * tc);
#pragma unroll
        for (int u = 0; u < 4; ++u) {
            float4 bv = bb[u];
#pragma unroll
            for (int p = 0; p < 2; ++p) {
                g[(r0 + p) * GS + 16 * tc + 4 * u + 0] = fmaxf(acc[p][4 * u + 0] + bv.x, 0.0f);
                g[(r0 + p) * GS + 16 * tc + 4 * u + 1] = fmaxf(acc[p][4 * u + 1] + bv.y, 0.0f);
                g[(r0 + p) * GS + 16 * tc + 4 * u + 2] = fmaxf(acc[p][4 * u + 2] + bv.z, 0.0f);
                g[(r0 + p) * GS + 16 * tc + 4 * u + 3] = fmaxf(acc[p][4 * u + 3] + bv.w, 0.0f);
            }
        }
    }
    __syncthreads();

    // Phase B: g2 = relu(g1 @ w2 + b2), K=512
    {
        float accB[2][16];
#pragma unroll
        for (int p = 0; p < 2; ++p)
#pragma unroll
            for (int i = 0; i < 16; ++i) accB[p][i] = 0.0f;

        for (int k4 = 0; k4 < 128; ++k4) {
            float4 av0 = *(const float4*)&g[(r0 + 0) * GS + 4 * k4];
            float4 av1 = *(const float4*)&g[(r0 + 1) * GS + 4 * k4];
            float a0[4] = {av0.x, av0.y, av0.z, av0.w};
            float a1[4] = {av1.x, av1.y, av1.z, av1.w};
#pragma unroll
            for (int u = 0; u < 4; ++u) {
                const float4* wr = (const float4*)(w2 + (4 * k4 + u) * 512 + 16 * tc);
#pragma unroll
                for (int q = 0; q < 4; ++q) {
                    float4 wv = wr[q];
                    accB[0][4 * q + 0] = fmaf(a0[u], wv.x, accB[0][4 * q + 0]);
                    accB[0][4 * q + 1] = fmaf(a0[u], wv.y, accB[0][4 * q + 1]);
                    accB[0][4 * q + 2] = fmaf(a0[u], wv.z, accB[0][4 * q + 2]);
                    accB[0][4 * q + 3] = fmaf(a0[u], wv.w, accB[0][4 * q + 3]);
                    accB[1][4 * q + 0] = fmaf(a1[u], wv.x, accB[1][4 * q + 0]);
                    accB[1][4 * q + 1] = fmaf(a1[u], wv.y, accB[1][4 * q + 1]);
                    accB[1][4 * q + 2] = fmaf(a1[u], wv.z, accB[1][4 * q + 2]);
                    accB[1][4 * q + 3] = fmaf(a1[u], wv.w, accB[1][4 * q + 3]);
                }
            }
        }
        __syncthreads();
        const float4* bb = (const float4*)(b2 + 16 * tc);
#pragma unroll
        for (int u = 0; u < 4; ++u) {
            float4 bv = bb[u];
#pragma unroll
            for (int p = 0; p < 2; ++p) {
                g[(r0 + p) * GS + 16 * tc + 4 * u + 0] = fmaxf(accB[p][4 * u + 0] + bv.x, 0.0f);
                g[(r0 + p) * GS + 16 * tc + 4 * u + 1] = fmaxf(accB[p][4 * u + 1] + bv.y, 0.0f);
                g[(r0 + p) * GS + 16 * tc + 4 * u + 2] = fmaxf(accB[p][4 * u + 2] + bv.z, 0.0f);
                g[(r0 + p) * GS + 16 * tc + 4 * u + 3] = fmaxf(accB[p][4 * u + 3] + bv.w, 0.0f);
            }
        }
    }
    __syncthreads();

    // Phase C: xhat = g2 @ w3 + b3, N=256 (8 cols/thread), K=512
    {
        float accC[2][8];
#pragma unroll
        for (int p = 0; p < 2; ++p)
#pragma unroll
            for (int i = 0; i < 8; ++i) accC[p][i] = 0.0f;

        for (int k4 = 0; k4 < 128; ++k4) {
            float4 av0 = *(const float4*)&g[(r0 + 0) * GS + 4 * k4];
            float4 av1 = *(const float4*)&g[(r0 + 1) * GS + 4 * k4];
            float a0[4] = {av0.x, av0.y, av0.z, av0.w};
            float a1[4] = {av1.x, av1.y, av1.z, av1.w};
#pragma unroll
            for (int u = 0; u < 4; ++u) {
                const float4* wr = (const float4*)(w3 + (4 * k4 + u) * 256 + 8 * tc);
                float4 w0 = wr[0], w1v = wr[1];
                accC[0][0] = fmaf(a0[u], w0.x,  accC[0][0]);
                accC[0][1] = fmaf(a0[u], w0.y,  accC[0][1]);
                accC[0][2] = fmaf(a0[u], w0.z,  accC[0][2]);
                accC[0][3] = fmaf(a0[u], w0.w,  accC[0][3]);
                accC[0][4] = fmaf(a0[u], w1v.x, accC[0][4]);
                accC[0][5] = fmaf(a0[u], w1v.y, accC[0][5]);
                accC[0][6] = fmaf(a0[u], w1v.z, accC[0][6]);
                accC[0][7] = fmaf(a0[u], w1v.w, accC[0][7]);
                accC[1][0] = fmaf(a1[u], w0.x,  accC[1][0]);
                accC[1][1] = fmaf(a1[u], w0.y,  accC[1][1]);
                accC[1][2] = fmaf(a1[u], w0.z,  accC[1][2]);
                accC[1][3] = fmaf(a1[u], w0.w,  accC[1][3]);
                accC[1][4] = fmaf(a1[u], w1v.x, accC[1][4]);
                accC[1][5] = fmaf(a1[u], w1v.y, accC[1][5]);
                accC[1][6] = fmaf(a1[u], w1v.z, accC[1][6]);
                accC[1][7] = fmaf(a1[u], w1v.w, accC[1][7]);
            }
        }
        const float4* bb = (const float4*)(b3 + 8 * tc);
        float4 bv0 = bb[0], bv1 = bb[1];
#pragma unroll
        for (int p = 0; p < 2; ++p) {
            float4 o0 = make_float4(accC[p][0] + bv0.x, accC[p][1] + bv0.y,
                                    accC[p][2] + bv0.z, accC[p][3] + bv0.w);
            float4 o1 = make_float4(accC[p][4] + bv1.x, accC[p][5] + bv1.y,
                                    accC[p][6] + bv1.z, accC[p][7] + bv1.w);
            float* dst = xhat + (size_t)(row0 + r0 + p) * 256 + 8 * tc;
            *(float4*)(dst)     = o0;
            *(float4*)(dst + 4) = o1;
        }
    }
}

extern "C" void kernel_launch(void* const* d_in, const int* in_sizes, int n_in,
                              void* d_out, int out_size, void* d_ws, size_t ws_size,
                              hipStream_t stream) {
    const float* x_seq  = (const float*)d_in[0];
    const float* tvec   = (const float*)d_in[1];
    const float* eps    = (const float*)d_in[2];
    const float* enc_w1 = (const float*)d_in[3];
    const float* enc_b1 = (const float*)d_in[4];
    const float* enc_w2 = (const float*)d_in[5];
    const float* enc_b2 = (const float*)d_in[6];
    const float* enc_w3 = (const float*)d_in[7];
    const float* enc_b3 = (const float*)d_in[8];
    const float* mu_w   = (const float*)d_in[9];
    const float* mu_b   = (const float*)d_in[10];
    const float* lv_w   = (const float*)d_in[11];
    const float* lv_b   = (const float*)d_in[12];
    const float* ode_w1 = (const float*)d_in[13];
    const float* ode_b1 = (const float*)d_in[14];
    const float* ode_w2 = (const float*)d_in[15];
    const float* ode_b2 = (const float*)d_in[16];
    const float* ode_w3 = (const float*)d_in[17];
    const float* ode_b3 = (const float*)d_in[18];
    const float* ln_g   = (const float*)d_in[19];
    const float* ln_b   = (const float*)d_in[20];
    const float* dec_w1 = (const float*)d_in[21];
    const float* dec_b1 = (const float*)d_in[22];
    const float* dec_w2 = (const float*)d_in[23];
    const float* dec_b2 = (const float*)d_in[24];
    const float* dec_w3 = (const float*)d_in[25];
    const float* dec_b3 = (const float*)d_in[26];
    float* out = (float*)d_out;

    enc_kernel<<<256, 256, 0, stream>>>(x_seq, eps, enc_w1, enc_b1, enc_w2, enc_b2,
                                        enc_w3, enc_b3, mu_w, mu_b, lv_w, lv_b, out);
    ode_kernel<<<256, 64, 0, stream>>>(tvec, ode_w1, ode_b1, ode_w2, ode_b2,
                                       ode_w3, ode_b3, ln_g, ln_b, out);
    dec_kernel<<<3200, 256, 0, stream>>>(out + OFF_ZT, dec_w1, dec_b1, dec_w2, dec_b2,
                                         dec_w3, dec_b3, out);
}